// Round 1
// baseline (119.125 us; speedup 1.0000x reference)
//
#include <hip/hip_runtime.h>
#include <hip/hip_bf16.h>
#include <stdint.h>

#define S_LEN 1024
#define BATCH 2
#define DM    768
#define NH    12
#define HD    64
#define W1    32
#define WIN   65
#define NQKV  2304
#define M_TOT 2048

typedef unsigned short u16;
typedef __attribute__((ext_vector_type(4))) float f4;
typedef __attribute__((ext_vector_type(4))) unsigned short us4;
typedef __attribute__((ext_vector_type(8))) unsigned short ushort8;
typedef __attribute__((ext_vector_type(8))) __bf16 bf16x8;
typedef __attribute__((ext_vector_type(4))) float f32x4;

__device__ inline float bf2f(u16 x) {
    union { unsigned u; float f; } z;
    z.u = ((unsigned)x) << 16;
    return z.f;
}
__device__ inline u16 f2bf(float x) {
    union { float f; unsigned u; } z;
    z.f = x;
    unsigned r = z.u + 0x7FFF + ((z.u >> 16) & 1);   // RNE
    return (u16)(r >> 16);
}

// async global->LDS, 16B per lane. LDS dest is wave-uniform base + lane*16.
__device__ __forceinline__ void g2l16(const u16* g, u16* l) {
    __builtin_amdgcn_global_load_lds(
        (const __attribute__((address_space(1))) unsigned int*)g,
        (__attribute__((address_space(3))) unsigned int*)l, 16, 0, 0);
}

// ---------------------------------------------------------------------------
// Kernel 1: prep. Blocks [0,768): X f32 -> Xb bf16. Blocks [768,1200):
// transpose+concat weights -> Wt bf16 [n][k]. (pooled zeroing removed:
// attention now writes per-block partials, no atomics.)
// ---------------------------------------------------------------------------
__global__ __launch_bounds__(256) void prep(
    const float* __restrict__ X,
    const float* __restrict__ Wq, const float* __restrict__ Wk,
    const float* __restrict__ Wv,
    u16* __restrict__ Xb, u16* __restrict__ Wt) {
    __shared__ float tile[64][69];
    const int t = threadIdx.x;
    const int bid = blockIdx.x;

    if (bid < 768) {
        const long base = (long)bid * 2048 + t * 8;
        f4 a = *(const f4*)&X[base];
        f4 b = *(const f4*)&X[base + 4];
        float v[8] = {a.x, a.y, a.z, a.w, b.x, b.y, b.z, b.w};
        ushort8 h;
        #pragma unroll
        for (int j = 0; j < 8; ++j) h[j] = f2bf(v[j]);
        *(ushort8*)&Xb[base] = h;
    } else {
        const int tw = bid - 768;           // 0..431
        const int n0 = (tw % 36) * 64;      // 0..2240
        const int k0 = (tw / 36) * 64;      // 0..704
        const int sel = n0 / DM;
        const int nl0 = n0 % DM;
        const float* W = (sel == 0) ? Wq : ((sel == 1) ? Wk : Wv);
        const int r = t >> 3;               // 0..31
        const int cg = t & 7;               // 0..7

        #pragma unroll
        for (int p = 0; p < 2; ++p) {
            int rr = r + p * 32;            // source row (k)
            long gb = (long)(k0 + rr) * DM + nl0 + cg * 8;
            *(f4*)&tile[rr][cg * 8]     = *(const f4*)&W[gb];
            *(f4*)&tile[rr][cg * 8 + 4] = *(const f4*)&W[gb + 4];
        }
        __syncthreads();
        #pragma unroll
        for (int p = 0; p < 2; ++p) {
            int rn = r + p * 32;            // output row (n)
            ushort8 h;
            #pragma unroll
            for (int jj = 0; jj < 8; ++jj)
                h[jj] = f2bf(tile[cg * 8 + jj][rn]);
            *(ushort8*)&Wt[(long)(n0 + rn) * DM + k0 + cg * 8] = h;
        }
    }
}

// ---------------------------------------------------------------------------
// Kernel 2: fused QKV GEMM, plain bf16 MFMA.
// 128x64 tile (MxN), BK=64, 576 blocks, 2x4 XCD swizzle.
// NEW: double-buffered LDS + global_load_lds (16B) staging with the XOR
// swizzle applied to the GLOBAL source address (LDS stays lane-linear),
// 2-phase prefetch: issue next tile's DMA before computing current tile,
// single drain+barrier per K-step. Hides the ~250cy L2 latency that the
// old reg-staged loop exposed on every one of the 12 K-steps.
// 48 KB LDS/block -> 3 blocks/CU.
// ---------------------------------------------------------------------------
__global__ __launch_bounds__(256) void qkv_gemm_mfma(
    const u16* __restrict__ Xb, const u16* __restrict__ Wt,
    const float* __restrict__ bq, const float* __restrict__ bk,
    const float* __restrict__ bv,
    u16* __restrict__ Q, u16* __restrict__ K, u16* __restrict__ Vt) {
    __shared__ u16 As[2][128 * 64];   // [row][8 chunks swizzled][8]
    __shared__ u16 Bs[2][64 * 64];

    const int bid = blockIdx.x;         // 0..575
    const int xcd = bid & 7;            // presumed XCD (RR dispatch)
    const int local = bid >> 3;         // 0..71 within XCD
    const int mt = (xcd & 1) * 8 + (local & 7);    // 0..15
    const int nt = (xcd >> 1) * 9 + (local >> 3);  // 0..35
    const int m0 = mt * 128;
    const int n0 = nt * 64;
    const int t = threadIdx.x;
    const int lane = t & 63;
    const int w = t >> 6;
    const int wm = w * 32;          // wave's M offset
    const int lrow = lane & 15;
    const int lq = lane >> 4;

    // Per-thread pre-swizzled global sources. LDS slot s holds global chunk
    // (row = s>>3, skc = (s&7) ^ (row&7)), so the read side's
    // (row*8 + (c ^ (row&7))) indexing finds chunk c of row.
    const u16* gA[4];
    const u16* gB[2];
    #pragma unroll
    for (int p = 0; p < 4; ++p) {
        int slot = p * 256 + t;
        int row = slot >> 3;
        int skc = (slot & 7) ^ (row & 7);
        gA[p] = Xb + (long)(m0 + row) * DM + skc * 8;
    }
    #pragma unroll
    for (int p = 0; p < 2; ++p) {
        int slot = p * 256 + t;
        int row = slot >> 3;
        int skc = (slot & 7) ^ (row & 7);
        gB[p] = Wt + (long)(n0 + row) * DM + skc * 8;
    }

#define STAGE(buf)                                                          \
    do {                                                                    \
        _Pragma("unroll")                                                   \
        for (int p = 0; p < 4; ++p)                                         \
            g2l16(gA[p], &As[buf][(p * 256 + w * 64) * 8]);                 \
        _Pragma("unroll")                                                   \
        for (int p = 0; p < 2; ++p)                                         \
            g2l16(gB[p], &Bs[buf][(p * 256 + w * 64) * 8]);                 \
        _Pragma("unroll")                                                   \
        for (int p = 0; p < 4; ++p) gA[p] += 64;                            \
        _Pragma("unroll")                                                   \
        for (int p = 0; p < 2; ++p) gB[p] += 64;                            \
    } while (0)

    const f32x4 fzero = {0.f, 0.f, 0.f, 0.f};
    f32x4 acc[2][4];
    #pragma unroll
    for (int i = 0; i < 2; ++i)
        #pragma unroll
        for (int j = 0; j < 4; ++j) acc[i][j] = fzero;

    STAGE(0);
    __syncthreads();    // drains vmcnt(0): tile 0 resident

    #pragma unroll
    for (int ks = 0; ks < 12; ++ks) {
        const int cb = ks & 1;
        if (ks < 11) STAGE(cb ^ 1);     // async prefetch overlaps compute
        #pragma unroll
        for (int kh = 0; kh < 2; ++kh) {
            const int c = kh * 4 + lq;
            bf16x8 ah[2], bh[4];
            #pragma unroll
            for (int i = 0; i < 2; ++i) {
                int ar = wm + i * 16 + lrow;
                ah[i] = *(const bf16x8*)&As[cb][(ar * 8 + (c ^ (ar & 7))) * 8];
            }
            #pragma unroll
            for (int j = 0; j < 4; ++j) {
                int br = j * 16 + lrow;
                bh[j] = *(const bf16x8*)&Bs[cb][(br * 8 + (c ^ (br & 7))) * 8];
            }
            #pragma unroll
            for (int i = 0; i < 2; ++i)
                #pragma unroll
                for (int j = 0; j < 4; ++j)
                    acc[i][j] = __builtin_amdgcn_mfma_f32_16x16x32_bf16(
                        ah[i], bh[j], acc[i][j], 0, 0, 0);
        }
        if (ks < 11) __syncthreads();   // drain prefetch + protect buffers
    }
#undef STAGE

    const int region = n0 / DM;     // 0=Q, 1=K, 2=V
    const int nc0 = n0 % DM;
    const float* bias = (region == 0) ? bq : ((region == 1) ? bk : bv);

    if (region < 2) {
        u16* Out = (region == 0) ? Q : K;
        #pragma unroll
        for (int j = 0; j < 4; ++j) {
            int col = nc0 + j * 16 + lrow;
            float bval = bias[col];
            #pragma unroll
            for (int i = 0; i < 2; ++i) {
                int row = m0 + wm + i * 16 + lq * 4;
                #pragma unroll
                for (int r = 0; r < 4; ++r)
                    Out[(long)(row + r) * DM + col] = f2bf(acc[i][j][r] + bval);
            }
        }
    } else {
        // V: write transposed bf16 Vt[b][h][dloc][s]; n-tile = one head
        const int h = nc0 >> 6;
        #pragma unroll
        for (int j = 0; j < 4; ++j) {
            int dloc = j * 16 + lrow;
            float bval = bias[nc0 + dloc];
            #pragma unroll
            for (int i = 0; i < 2; ++i) {
                int row = m0 + wm + i * 16 + lq * 4;   // global s (incl batch)
                int b = row >> 10, sl = row & 1023;
                us4 pk;
                #pragma unroll
                for (int r = 0; r < 4; ++r) pk[r] = f2bf(acc[i][j][r] + bval);
                *(us4*)&Vt[(((long)(b * NH + h) * 64 + dloc) << 10) + sl] = pk;
            }
        }
    }
}

// ---------------------------------------------------------------------------
// Kernel 3: MFMA flash attention + pooled partial (plain bf16 QK^T).
// Block (b, h, 32 queries) = 128 threads (2 waves of 16 queries); 96-key
// window. NEW: no atomics — waves reduce into LDS, block writes its 64
// pooled partials once to partial[b][h][sblk][64]; fc sums the 32 partials.
// ---------------------------------------------------------------------------
__global__ __launch_bounds__(128) void attn_pool_mfma(
    const u16* __restrict__ Q, const u16* __restrict__ K,
    const u16* __restrict__ Vt, float* __restrict__ partial) {
    __shared__ u16 vt[64][104];        // V^T window: [d][key 96 + pad 8]
    __shared__ u16 pl[2][16][104];     // per-wave P: [wave][query row][key]
    __shared__ float pr[2][64];        // per-wave pooled partials
    const int b = blockIdx.z, h = blockIdx.y;
    const int s0 = blockIdx.x * 32;
    const int t = threadIdx.x;
    const int k0 = s0 - 32;

    // stage V^T window: 64 d x 96 keys = 768 8-elem chunks, 6 iters x 128 thr
    const u16* vtg = Vt + ((size_t)(b * NH + h) * 64) * 1024;
    #pragma unroll
    for (int it = 0; it < 6; ++it) {
        int slot = it * 128 + t;        // 0..767
        int d = slot / 12, kc = slot % 12;
        int kbase = k0 + kc * 8;
        if (kbase >= 0 && kbase + 7 < S_LEN) {
            *(ushort8*)&vt[d][kc * 8] = *(const ushort8*)&vtg[d * 1024 + kbase];
        } else {
            #pragma unroll
            for (int j = 0; j < 8; ++j) {
                int kk = kbase + j;
                int kcl = kk < 0 ? 0 : (kk > S_LEN - 1 ? S_LEN - 1 : kk);
                vt[d][kc * 8 + j] = vtg[d * 1024 + kcl];
            }
        }
    }
    __syncthreads();

    const int w = t >> 6, lane = t & 63;
    const int cl = lane & 15, q = lane >> 4;

    // ---- scores: S = Q . K^T (6 key-tiles of 16) ----
    const f32x4 fzero = {0.f, 0.f, 0.f, 0.f};
    f32x4 accS[6];
    #pragma unroll
    for (int n = 0; n < 6; ++n) accS[n] = fzero;

    const long qrow = (long)(b * S_LEN + s0 + w * 16 + cl);
    bf16x8 aq[2];
    #pragma unroll
    for (int ks = 0; ks < 2; ++ks)
        aq[ks] = *(const bf16x8*)&Q[qrow * DM + h * HD + ks * 32 + q * 8];
    #pragma unroll
    for (int n = 0; n < 6; ++n) {
        int key = k0 + n * 16 + cl;
        int kcl = key < 0 ? 0 : (key > S_LEN - 1 ? S_LEN - 1 : key);
        long ka = (long)(b * S_LEN + kcl) * DM + h * HD;
        #pragma unroll
        for (int ks = 0; ks < 2; ++ks) {
            bf16x8 bk = *(const bf16x8*)&K[ka + ks * 32 + q * 8];
            accS[n] = __builtin_amdgcn_mfma_f32_16x16x32_bf16(aq[ks], bk, accS[n], 0, 0, 0);
        }
    }

    // ---- softmax (unnormalized) in C-layout: col=cl(key), row=q*4+r ----
    float l4[4] = {0.f, 0.f, 0.f, 0.f};
    #pragma unroll
    for (int n = 0; n < 6; ++n) {
        int key = k0 + n * 16 + cl;
        #pragma unroll
        for (int r = 0; r < 4; ++r) {
            int s = s0 + w * 16 + q * 4 + r;
            bool valid = (key >= s - W1) && (key <= s + W1) && (key >= 0) && (key < S_LEN);
            float p = valid ? __expf(accS[n][r] * 0.125f) : 0.f;
            accS[n][r] = p;
            l4[r] += p;
        }
    }
    #pragma unroll
    for (int m = 1; m <= 8; m <<= 1)
        #pragma unroll
        for (int r = 0; r < 4; ++r) l4[r] += __shfl_xor(l4[r], m, 64);

    // ---- P -> LDS in A-layout ----
    #pragma unroll
    for (int n = 0; n < 6; ++n)
        #pragma unroll
        for (int r = 0; r < 4; ++r)
            pl[w][q * 4 + r][n * 16 + cl] = f2bf(accS[n][r]);

    // ---- O = P . V (MFMA over 3 key-chunks of 32) ----
    f32x4 accO[4];
    #pragma unroll
    for (int n = 0; n < 4; ++n) accO[n] = fzero;
    bf16x8 ap[3];
    #pragma unroll
    for (int ks = 0; ks < 3; ++ks)
        ap[ks] = *(const bf16x8*)&pl[w][cl][ks * 32 + q * 8];
    #pragma unroll
    for (int n = 0; n < 4; ++n)
        #pragma unroll
        for (int ks = 0; ks < 3; ++ks) {
            bf16x8 bv = *(const bf16x8*)&vt[n * 16 + cl][ks * 32 + q * 8];
            accO[n] = __builtin_amdgcn_mfma_f32_16x16x32_bf16(ap[ks], bv, accO[n], 0, 0, 0);
        }

    // ---- normalize rows, pool over the wave's 16 queries, LDS reduce ----
    float rcp4[4];
    #pragma unroll
    for (int r = 0; r < 4; ++r) rcp4[r] = 1.0f / l4[r];
    #pragma unroll
    for (int n = 0; n < 4; ++n) {
        float pp = 0.f;
        #pragma unroll
        for (int r = 0; r < 4; ++r) pp += accO[n][r] * rcp4[r];
        pp += __shfl_xor(pp, 16, 64);
        pp += __shfl_xor(pp, 32, 64);
        if (q == 0) pr[w][n * 16 + cl] = pp;
    }
    __syncthreads();
    if (t < 64) {
        long pb = (((long)(b * NH + h) * 32) + blockIdx.x) * 64 + t;
        partial[pb] = pr[0][t] + pr[1][t];
    }
}

// ---------------------------------------------------------------------------
// Kernel 4: out = relu((sum_sblk partial)/S @ Wfc + bfc) -> f32.
// 24 blocks = (batch, col64). Stages the pooled row (sum of 32 partials)
// into LDS first (96 coalesced loads/thread), then the GEMV loop.
// ---------------------------------------------------------------------------
__global__ __launch_bounds__(256) void fc_relu_f(
    const float* __restrict__ partial, const float* __restrict__ Wfc,
    const float* __restrict__ bfc, float* __restrict__ out) {
    __shared__ float red[4][64];
    __shared__ float ps[768];
    const int t = threadIdx.x;
    const int nb = blockIdx.x % 12;     // col tile
    const int bb = blockIdx.x / 12;     // batch

    for (int d = t; d < DM; d += 256) {
        const float* pp = partial + ((long)(bb * NH + (d >> 6)) * 32) * 64 + (d & 63);
        float s = 0.f;
        #pragma unroll
        for (int sb = 0; sb < 32; ++sb) s += pp[sb * 64];
        ps[d] = s;
    }
    __syncthreads();

    const int nn = t & 63;
    const int dg = t >> 6;              // 0..3
    const int n = nb * 64 + nn;
    float s = 0.f;
    for (int d = dg * 192; d < dg * 192 + 192; ++d)
        s += ps[d] * Wfc[(long)d * DM + n];
    red[dg][nn] = s;
    __syncthreads();
    if (t < 64) {
        float sum = red[0][t] + red[1][t] + red[2][t] + red[3][t];
        sum = sum * (1.0f / (float)S_LEN) + bfc[nb * 64 + t];
        sum = sum > 0.f ? sum : 0.f;
        out[bb * DM + nb * 64 + t] = sum;
    }
}

// ---------------------------------------------------------------------------
extern "C" void kernel_launch(void* const* d_in, const int* in_sizes, int n_in,
                              void* d_out, int out_size, void* d_ws, size_t ws_size,
                              hipStream_t stream) {
    const float* X   = (const float*)d_in[0];
    const float* Wq  = (const float*)d_in[1];
    const float* bq  = (const float*)d_in[2];
    const float* Wk  = (const float*)d_in[3];
    const float* bk  = (const float*)d_in[4];
    const float* Wv  = (const float*)d_in[5];
    const float* bv  = (const float*)d_in[6];
    const float* Wfc = (const float*)d_in[7];
    const float* bfc = (const float*)d_in[8];

    char* ws = (char*)d_ws;
    const size_t SZ_XB = (size_t)M_TOT * DM * 2;              // 3,145,728
    const size_t SZ_WB = (size_t)NQKV * DM * 2;               // 3,538,944
    u16* Xb = (u16*)(ws);
    u16* Wt = (u16*)(ws + SZ_XB);
    u16* Q  = (u16*)(ws + SZ_XB + SZ_WB);
    u16* K  = (u16*)(ws + 2 * SZ_XB + SZ_WB);
    u16* Vt = (u16*)(ws + 3 * SZ_XB + SZ_WB);
    float* partial = (float*)(ws + 4 * SZ_XB + SZ_WB);        // [2][12][32][64] f32

    prep<<<1200, 256, 0, stream>>>(X, Wq, Wk, Wv, Xb, Wt);

    qkv_gemm_mfma<<<576, 256, 0, stream>>>(
        Xb, Wt, bq, bk, bv, Q, K, Vt);

    attn_pool_mfma<<<dim3(32, NH, BATCH), 128, 0, stream>>>(
        Q, K, Vt, partial);

    fc_relu_f<<<24, 256, 0, stream>>>(partial, Wfc, bfc, (float*)d_out);
}